// Round 1
// baseline (486.325 us; speedup 1.0000x reference)
//
#include <hip/hip_runtime.h>
#include <math.h>

#define NE 65536
#define NN 8192

// ws layout (bytes)
#define WS_A        0u           // 65536*512*4 = 134217728
#define WS_X        134217728u   // 8192*128*4  = 4194304
#define WS_C        138412032u   // 4*10*128*128*4 = 2621440
#define WS_COUNTS   141033472u   // 8192*4
#define WS_CURSOR   141066240u   // 8192*4
#define WS_ROWSTART 141099008u   // 8193*4 (pad to 33024)
#define WS_ELIST    141132032u   // 65536*4

// ---------------- CSR build ----------------
__global__ void k_count(const int* __restrict__ eidx, int* __restrict__ counts) {
    int e = blockIdx.x * 256 + threadIdx.x;
    if (e < NE) atomicAdd(&counts[eidx[NE + e]], 1);
}

__global__ __launch_bounds__(1024) void k_scan(const int* __restrict__ counts,
                                               int* __restrict__ row_start,
                                               int* __restrict__ cursor) {
    __shared__ int sd[1024];
    int t = threadIdx.x;
    int c[8];
    int s = 0;
    #pragma unroll
    for (int i = 0; i < 8; ++i) { c[i] = counts[t * 8 + i]; s += c[i]; }
    sd[t] = s;
    __syncthreads();
    for (int off = 1; off < 1024; off <<= 1) {
        int v = (t >= off) ? sd[t - off] : 0;
        __syncthreads();
        sd[t] += v;
        __syncthreads();
    }
    int run = (t == 0) ? 0 : sd[t - 1];
    #pragma unroll
    for (int i = 0; i < 8; ++i) {
        row_start[t * 8 + i] = run;
        cursor[t * 8 + i] = run;
        run += c[i];
    }
    if (t == 1023) row_start[8192] = run;
}

__global__ void k_scatter(const int* __restrict__ eidx, int* __restrict__ cursor,
                          int* __restrict__ elist) {
    int e = blockIdx.x * 256 + threadIdx.x;
    if (e < NE) {
        int p = atomicAdd(&cursor[eidx[NE + e]], 1);
        elist[p] = e;
    }
}

// ---------------- x = node_feats @ W_up / sqrt(128) ----------------
// 16 nodes per block, 256 threads: thread = (mc = t&127, half = t>>7) -> 8 nodes each
__global__ __launch_bounds__(256) void k_x(const float* __restrict__ nf,
                                           const float* __restrict__ Wup,
                                           float* __restrict__ x) {
    __shared__ float nf_s[16][128];
    int n0 = blockIdx.x * 16;
    int t = threadIdx.x;
    for (int i = t; i < 16 * 128; i += 256) nf_s[i >> 7][i & 127] = nf[n0 * 128 + i];
    __syncthreads();
    int mc = t & 127, half = t >> 7;
    float acc[8];
    #pragma unroll
    for (int j = 0; j < 8; ++j) acc[j] = 0.f;
    for (int k = 0; k < 128; ++k) {
        float w = Wup[k * 128 + mc];
        #pragma unroll
        for (int j = 0; j < 8; ++j) acc[j] += nf_s[half * 8 + j][k] * w;
    }
    const float rs = 0.08838834764831845f;  // 1/sqrt(128)
    #pragma unroll
    for (int j = 0; j < 8; ++j) x[(n0 + half * 8 + j) * 128 + mc] = acc[j] * rs;
}

// ---------------- C[l][z][u][u'] = scale * sum_v W_lin[l][u][v] * W_skip[l][v][z][u'] ----------------
// one block per (l,z); stage W_skip slice in LDS (64 KB)
__global__ __launch_bounds__(256) void k_C(const float* __restrict__ Wlin,
                                           const float* __restrict__ Wskip,
                                           float* __restrict__ C) {
    __shared__ float S[128 * 128];
    int l = blockIdx.x / 10, z = blockIdx.x % 10;
    int t = threadIdx.x;
    for (int i = t; i < 128 * 128; i += 256) {
        int v = i >> 7, u2 = i & 127;
        S[i] = Wskip[((l * 128 + v) * 10 + z) * 128 + u2];
    }
    __syncthreads();
    int u2 = t & 127, uh = t >> 7;
    const float scale = 3.0881618e-04f;  // (1/sqrt(128)/8) * (1/sqrt(1280))
    const float* wl = Wlin + l * 128 * 128;
    for (int i = 0; i < 64; ++i) {
        int u = uh * 64 + i;
        float acc = 0.f;
        #pragma unroll 4
        for (int v = 0; v < 128; ++v) acc += wl[u * 128 + v] * S[v * 128 + u2];
        C[((l * 10 + z) * 128 + u) * 128 + u2] = acc * scale;
    }
}

// ---------------- edge MLP + W4 GEMM + x-gather epilogue -> A[e][512] ----------------
// 32 edges per block, 256 threads (4 waves). GEMM micro-tile 8 rows x 8 cols per thread.
__global__ __launch_bounds__(256) void k_edge(const float* __restrict__ ef,
                                              const int* __restrict__ eidx,
                                              const float* __restrict__ W1, const float* __restrict__ b1,
                                              const float* __restrict__ W2, const float* __restrict__ b2,
                                              const float* __restrict__ W3, const float* __restrict__ b3,
                                              const float* __restrict__ W4, const float* __restrict__ b4,
                                              const float* __restrict__ x,
                                              float* __restrict__ A) {
    __shared__ float ef_s[32][8];
    __shared__ float ha[32][65];
    __shared__ float hb[32][65];
    int t = threadIdx.x;
    int e0 = blockIdx.x * 32;
    ef_s[t >> 3][t & 7] = ef[e0 * 8 + t];
    __syncthreads();
    int lane = t & 63, wv = t >> 6;
    // layer1: 8 -> 64
    #pragma unroll
    for (int j = 0; j < 8; ++j) {
        int e = wv + 4 * j;
        float s = b1[lane];
        #pragma unroll
        for (int i = 0; i < 8; ++i) s += ef_s[e][i] * W1[i * 64 + lane];
        ha[e][lane] = s / (1.f + expf(-s));
    }
    __syncthreads();
    // layer2: 64 -> 64
    #pragma unroll
    for (int j = 0; j < 8; ++j) {
        int e = wv + 4 * j;
        float s = b2[lane];
        #pragma unroll 8
        for (int i = 0; i < 64; ++i) s += ha[e][i] * W2[i * 64 + lane];
        hb[e][lane] = s / (1.f + expf(-s));
    }
    __syncthreads();
    // layer3: 64 -> 64 (back into ha)
    #pragma unroll
    for (int j = 0; j < 8; ++j) {
        int e = wv + 4 * j;
        float s = b3[lane];
        #pragma unroll 8
        for (int i = 0; i < 64; ++i) s += hb[e][i] * W3[i * 64 + lane];
        ha[e][lane] = s / (1.f + expf(-s));
    }
    __syncthreads();
    // GEMM: (32 x 64) @ (64 x 512). wave rg owns rows rg*8..rg*8+7; cols cl + 64*j
    int cl = t & 63, rg = t >> 6;
    float acc[8][8];
    #pragma unroll
    for (int r = 0; r < 8; ++r)
        #pragma unroll
        for (int j = 0; j < 8; ++j) acc[r][j] = 0.f;
    for (int k = 0; k < 64; ++k) {
        float w4v[8];
        #pragma unroll
        for (int j = 0; j < 8; ++j) w4v[j] = W4[k * 512 + cl + 64 * j];
        #pragma unroll
        for (int r = 0; r < 8; ++r) {
            float hv = ha[rg * 8 + r][k];
            #pragma unroll
            for (int j = 0; j < 8; ++j) acc[r][j] += hv * w4v[j];
        }
    }
    float b4v[8];
    #pragma unroll
    for (int j = 0; j < 8; ++j) b4v[j] = b4[cl + 64 * j];
    #pragma unroll
    for (int r = 0; r < 8; ++r) {
        int e = e0 + rg * 8 + r;
        int src = eidx[e];
        float xv0 = x[src * 128 + cl];
        float xv1 = x[src * 128 + cl + 64];
        #pragma unroll
        for (int j = 0; j < 8; ++j) {
            float tpw = acc[r][j] + b4v[j];
            A[e * 512 + cl + 64 * j] = tpw * ((j & 1) ? xv1 : xv0);
        }
    }
}

// ---------------- per-node gather + C[z] contraction ----------------
// block = one node, 256 threads: (mc = t&127, hi = t>>7 selects dt 0..7 / 8..15)
#define CAP 128
__global__ __launch_bounds__(256) void k_gather(const float* __restrict__ A,
                                                const float* __restrict__ Y,
                                                const float* __restrict__ C,
                                                const float* __restrict__ na,
                                                const int* __restrict__ row_start,
                                                const int* __restrict__ elist,
                                                float* __restrict__ out) {
    __shared__ int el_s[CAP];
    __shared__ float msgs_s[128 * 17];
    __shared__ float out_s[128 * 17];
    int n = blockIdx.x;
    int t = threadIdx.x;
    int r0 = row_start[n], r1 = row_start[n + 1];
    int k = r1 - r0;
    for (int i = t; i < k && i < CAP; i += 256) el_s[i] = elist[r0 + i];
    __syncthreads();
    if (t == 0 && k <= CAP) {  // canonical order -> deterministic f32 sums
        for (int i = 1; i < k; ++i) {
            int key = el_s[i];
            int j = i - 1;
            while (j >= 0 && el_s[j] > key) { el_s[j + 1] = el_s[j]; --j; }
            el_s[j + 1] = key;
        }
    }
    __syncthreads();
    int mc = t & 127, hi = t >> 7;
    float acc[8];
    #pragma unroll
    for (int q = 0; q < 8; ++q) acc[q] = 0.f;
    for (int j = 0; j < k; ++j) {
        int e = (j < CAP) ? el_s[j] : elist[r0 + j];
        const float* Ae = A + (size_t)e * 512;
        const float* Ye = Y + e * 16 + hi * 8;
        float y[8];
        #pragma unroll
        for (int q = 0; q < 8; ++q) y[q] = Ye[q];
        if (hi == 0) {
            float a0 = Ae[mc], a1 = Ae[128 + mc], a2 = Ae[256 + mc];
            acc[0] += a0 * y[0];
            acc[1] += a1 * y[1]; acc[2] += a1 * y[2]; acc[3] += a1 * y[3];
            acc[4] += a2 * y[4]; acc[5] += a2 * y[5]; acc[6] += a2 * y[6]; acc[7] += a2 * y[7];
        } else {
            float a2 = Ae[256 + mc], a3 = Ae[384 + mc];
            acc[0] += a2 * y[0];
            #pragma unroll
            for (int q = 1; q < 8; ++q) acc[q] += a3 * y[q];
        }
    }
    #pragma unroll
    for (int q = 0; q < 8; ++q) msgs_s[mc * 17 + hi * 8 + q] = acc[q];
    __syncthreads();
    int z = 0;
    #pragma unroll
    for (int w = 1; w < 10; ++w)
        if (na[n * 10 + w] > 0.5f) z = w;
    float o[8];
    #pragma unroll
    for (int q = 0; q < 8; ++q) o[q] = 0.f;
    if (hi == 0) {
        const float* C0 = C + (0 * 10 + z) * 16384 + mc;
        const float* C1 = C + (1 * 10 + z) * 16384 + mc;
        const float* C2 = C + (2 * 10 + z) * 16384 + mc;
        #pragma unroll 4
        for (int u = 0; u < 128; ++u) {
            float c0 = C0[u * 128], c1 = C1[u * 128], c2 = C2[u * 128];
            const float* m = &msgs_s[u * 17];
            o[0] += m[0] * c0;
            o[1] += m[1] * c1; o[2] += m[2] * c1; o[3] += m[3] * c1;
            o[4] += m[4] * c2; o[5] += m[5] * c2; o[6] += m[6] * c2; o[7] += m[7] * c2;
        }
    } else {
        const float* C2 = C + (2 * 10 + z) * 16384 + mc;
        const float* C3 = C + (3 * 10 + z) * 16384 + mc;
        #pragma unroll 4
        for (int u = 0; u < 128; ++u) {
            float c2 = C2[u * 128], c3 = C3[u * 128];
            const float* m = &msgs_s[u * 17] + 8;
            o[0] += m[0] * c2;
            #pragma unroll
            for (int q = 1; q < 8; ++q) o[q] += m[q] * c3;
        }
    }
    #pragma unroll
    for (int q = 0; q < 8; ++q) out_s[mc * 17 + hi * 8 + q] = o[q];
    __syncthreads();
    // coalesced store: thread t writes out[n*2048 + t*8 .. +7]
    int u_ = t >> 1;
    int dbase = (t & 1) * 8;
    const float* src = &out_s[u_ * 17 + dbase];
    float4 v0 = make_float4(src[0], src[1], src[2], src[3]);
    float4 v1 = make_float4(src[4], src[5], src[6], src[7]);
    float4* dst = (float4*)(out + (size_t)n * 2048 + t * 8);
    dst[0] = v0;
    dst[1] = v1;
}

extern "C" void kernel_launch(void* const* d_in, const int* in_sizes, int n_in,
                              void* d_out, int out_size, void* d_ws, size_t ws_size,
                              hipStream_t stream) {
    const float* na   = (const float*)d_in[0];
    const float* nf   = (const float*)d_in[1];
    const float* ea   = (const float*)d_in[2];
    const float* ef   = (const float*)d_in[3];
    const int*   eidx = (const int*)d_in[4];
    const float* Wup  = (const float*)d_in[5];
    const float* W1   = (const float*)d_in[6];
    const float* b1   = (const float*)d_in[7];
    const float* W2   = (const float*)d_in[8];
    const float* b2   = (const float*)d_in[9];
    const float* W3   = (const float*)d_in[10];
    const float* b3   = (const float*)d_in[11];
    const float* W4   = (const float*)d_in[12];
    const float* b4   = (const float*)d_in[13];
    const float* Wlin = (const float*)d_in[14];
    const float* Wskip= (const float*)d_in[15];
    float* out = (float*)d_out;

    char* ws = (char*)d_ws;
    float* A        = (float*)(ws + WS_A);
    float* x        = (float*)(ws + WS_X);
    float* C        = (float*)(ws + WS_C);
    int*   counts   = (int*)(ws + WS_COUNTS);
    int*   cursor   = (int*)(ws + WS_CURSOR);
    int*   rowstart = (int*)(ws + WS_ROWSTART);
    int*   elist    = (int*)(ws + WS_ELIST);

    hipMemsetAsync(counts, 0, NN * sizeof(int), stream);
    k_count<<<NE / 256, 256, 0, stream>>>(eidx, counts);
    k_scan<<<1, 1024, 0, stream>>>(counts, rowstart, cursor);
    k_scatter<<<NE / 256, 256, 0, stream>>>(eidx, cursor, elist);
    k_x<<<NN / 16, 256, 0, stream>>>(nf, Wup, x);
    k_C<<<40, 256, 0, stream>>>(Wlin, Wskip, C);
    k_edge<<<NE / 32, 256, 0, stream>>>(ef, eidx, W1, b1, W2, b2, W3, b3, W4, b4, x, A);
    k_gather<<<NN, 256, 0, stream>>>(A, ea, C, na, rowstart, elist, out);
}

// Round 2
// 316.158 us; speedup vs baseline: 1.5382x; 1.5382x over previous
//
#include <hip/hip_runtime.h>
#include <math.h>

#define NE 65536
#define NN 8192

// ws layout (bytes)
#define WS_A        0u           // 65536*512*4 = 134217728
#define WS_X        134217728u   // 8192*128*4  = 4194304
#define WS_C        138412032u   // 4*10*128*128*4 = 2621440
#define WS_COUNTS   141033472u   // 8192*4
#define WS_CURSOR   141066240u   // 8192*4
#define WS_ROWSTART 141099008u   // 8193*4 (pad to 33024)
#define WS_ELIST    141132032u   // 65536*4

// ---------------- CSR build ----------------
__global__ void k_count(const int* __restrict__ eidx, int* __restrict__ counts) {
    int e = blockIdx.x * 256 + threadIdx.x;
    if (e < NE) atomicAdd(&counts[eidx[NE + e]], 1);
}

__global__ __launch_bounds__(1024) void k_scan(const int* __restrict__ counts,
                                               int* __restrict__ row_start,
                                               int* __restrict__ cursor) {
    __shared__ int sd[1024];
    int t = threadIdx.x;
    int c[8];
    int s = 0;
    #pragma unroll
    for (int i = 0; i < 8; ++i) { c[i] = counts[t * 8 + i]; s += c[i]; }
    sd[t] = s;
    __syncthreads();
    for (int off = 1; off < 1024; off <<= 1) {
        int v = (t >= off) ? sd[t - off] : 0;
        __syncthreads();
        sd[t] += v;
        __syncthreads();
    }
    int run = (t == 0) ? 0 : sd[t - 1];
    #pragma unroll
    for (int i = 0; i < 8; ++i) {
        row_start[t * 8 + i] = run;
        cursor[t * 8 + i] = run;
        run += c[i];
    }
    if (t == 1023) row_start[8192] = run;
}

__global__ void k_scatter(const int* __restrict__ eidx, int* __restrict__ cursor,
                          int* __restrict__ elist) {
    int e = blockIdx.x * 256 + threadIdx.x;
    if (e < NE) {
        int p = atomicAdd(&cursor[eidx[NE + e]], 1);
        elist[p] = e;
    }
}

// ---------------- x = node_feats @ W_up / sqrt(128) ----------------
__global__ __launch_bounds__(256) void k_x(const float* __restrict__ nf,
                                           const float* __restrict__ Wup,
                                           float* __restrict__ x) {
    __shared__ float nf_s[16][128];
    int n0 = blockIdx.x * 16;
    int t = threadIdx.x;
    for (int i = t; i < 16 * 128; i += 256) nf_s[i >> 7][i & 127] = nf[n0 * 128 + i];
    __syncthreads();
    int mc = t & 127, half = t >> 7;
    float acc[8];
    #pragma unroll
    for (int j = 0; j < 8; ++j) acc[j] = 0.f;
    for (int k = 0; k < 128; ++k) {
        float w = Wup[k * 128 + mc];
        #pragma unroll
        for (int j = 0; j < 8; ++j) acc[j] += nf_s[half * 8 + j][k] * w;
    }
    const float rs = 0.08838834764831845f;  // 1/sqrt(128)
    #pragma unroll
    for (int j = 0; j < 8; ++j) x[(n0 + half * 8 + j) * 128 + mc] = acc[j] * rs;
}

// ---------------- C[l][z][u][u'] = scale * sum_v W_lin[l][u][v] * W_skip[l][v][z][u'] ----------------
// RESTRUCTURED (R1): 320 blocks = (l,z) x 8 u-tiles of 16. Wlin tile (8KB) in LDS,
// Wskip streamed coalesced from global (L2). 8 outputs/thread, acc in registers.
__global__ __launch_bounds__(256) void k_C(const float* __restrict__ Wlin,
                                           const float* __restrict__ Wskip,
                                           float* __restrict__ C) {
    __shared__ float wl_s[16][128];
    int b = blockIdx.x;
    int lz = b >> 3, ut = b & 7;
    int l = lz / 10, z = lz % 10;
    int t = threadIdx.x;
    for (int i = t; i < 16 * 128; i += 256) {
        int u = i >> 7, v = i & 127;
        wl_s[u][v] = Wlin[(l * 128 + ut * 16 + u) * 128 + v];
    }
    __syncthreads();
    int u2 = t & 127, uh = t >> 7;  // uh=0/1 -> u rows uh*8 .. uh*8+7 within tile
    float acc[8];
    #pragma unroll
    for (int r = 0; r < 8; ++r) acc[r] = 0.f;
    const float* Wsk = Wskip + ((size_t)l * 128 * 10 + z) * 128 + u2;  // stride over v: 1280
    for (int v = 0; v < 128; v += 4) {
        float s0 = Wsk[(size_t)(v + 0) * 1280];
        float s1 = Wsk[(size_t)(v + 1) * 1280];
        float s2 = Wsk[(size_t)(v + 2) * 1280];
        float s3 = Wsk[(size_t)(v + 3) * 1280];
        #pragma unroll
        for (int r = 0; r < 8; ++r) {
            int u = uh * 8 + r;
            acc[r] += wl_s[u][v] * s0 + wl_s[u][v + 1] * s1
                    + wl_s[u][v + 2] * s2 + wl_s[u][v + 3] * s3;
        }
    }
    const float scale = 3.0881618e-04f;  // (1/sqrt(128)/8) * (1/sqrt(1280))
    #pragma unroll
    for (int r = 0; r < 8; ++r) {
        int u = ut * 16 + uh * 8 + r;
        C[((l * 10 + z) * 128 + u) * 128 + u2] = acc[r] * scale;
    }
}

// ---------------- edge MLP + W4 GEMM + x-gather epilogue -> A[e][512] ----------------
__global__ __launch_bounds__(256) void k_edge(const float* __restrict__ ef,
                                              const int* __restrict__ eidx,
                                              const float* __restrict__ W1, const float* __restrict__ b1,
                                              const float* __restrict__ W2, const float* __restrict__ b2,
                                              const float* __restrict__ W3, const float* __restrict__ b3,
                                              const float* __restrict__ W4, const float* __restrict__ b4,
                                              const float* __restrict__ x,
                                              float* __restrict__ A) {
    __shared__ float ef_s[32][8];
    __shared__ float ha[32][65];
    __shared__ float hb[32][65];
    int t = threadIdx.x;
    int e0 = blockIdx.x * 32;
    ef_s[t >> 3][t & 7] = ef[e0 * 8 + t];
    __syncthreads();
    int lane = t & 63, wv = t >> 6;
    #pragma unroll
    for (int j = 0; j < 8; ++j) {
        int e = wv + 4 * j;
        float s = b1[lane];
        #pragma unroll
        for (int i = 0; i < 8; ++i) s += ef_s[e][i] * W1[i * 64 + lane];
        ha[e][lane] = s / (1.f + expf(-s));
    }
    __syncthreads();
    #pragma unroll
    for (int j = 0; j < 8; ++j) {
        int e = wv + 4 * j;
        float s = b2[lane];
        #pragma unroll 8
        for (int i = 0; i < 64; ++i) s += ha[e][i] * W2[i * 64 + lane];
        hb[e][lane] = s / (1.f + expf(-s));
    }
    __syncthreads();
    #pragma unroll
    for (int j = 0; j < 8; ++j) {
        int e = wv + 4 * j;
        float s = b3[lane];
        #pragma unroll 8
        for (int i = 0; i < 64; ++i) s += hb[e][i] * W3[i * 64 + lane];
        ha[e][lane] = s / (1.f + expf(-s));
    }
    __syncthreads();
    int cl = t & 63, rg = t >> 6;
    float acc[8][8];
    #pragma unroll
    for (int r = 0; r < 8; ++r)
        #pragma unroll
        for (int j = 0; j < 8; ++j) acc[r][j] = 0.f;
    for (int k = 0; k < 64; ++k) {
        float w4v[8];
        #pragma unroll
        for (int j = 0; j < 8; ++j) w4v[j] = W4[k * 512 + cl + 64 * j];
        #pragma unroll
        for (int r = 0; r < 8; ++r) {
            float hv = ha[rg * 8 + r][k];
            #pragma unroll
            for (int j = 0; j < 8; ++j) acc[r][j] += hv * w4v[j];
        }
    }
    float b4v[8];
    #pragma unroll
    for (int j = 0; j < 8; ++j) b4v[j] = b4[cl + 64 * j];
    #pragma unroll
    for (int r = 0; r < 8; ++r) {
        int e = e0 + rg * 8 + r;
        int src = eidx[e];
        float xv0 = x[src * 128 + cl];
        float xv1 = x[src * 128 + cl + 64];
        #pragma unroll
        for (int j = 0; j < 8; ++j) {
            float tpw = acc[r][j] + b4v[j];
            A[e * 512 + cl + 64 * j] = tpw * ((j & 1) ? xv1 : xv0);
        }
    }
}

// ---------------- per-node gather + C[z] contraction ----------------
#define CAP 128
__global__ __launch_bounds__(256) void k_gather(const float* __restrict__ A,
                                                const float* __restrict__ Y,
                                                const float* __restrict__ C,
                                                const float* __restrict__ na,
                                                const int* __restrict__ row_start,
                                                const int* __restrict__ elist,
                                                float* __restrict__ out) {
    __shared__ int el_s[CAP];
    __shared__ float msgs_s[128 * 17];
    __shared__ float out_s[128 * 17];
    int n = blockIdx.x;
    int t = threadIdx.x;
    int r0 = row_start[n], r1 = row_start[n + 1];
    int k = r1 - r0;
    for (int i = t; i < k && i < CAP; i += 256) el_s[i] = elist[r0 + i];
    __syncthreads();
    if (t == 0 && k <= CAP) {  // canonical order -> deterministic f32 sums
        for (int i = 1; i < k; ++i) {
            int key = el_s[i];
            int j = i - 1;
            while (j >= 0 && el_s[j] > key) { el_s[j + 1] = el_s[j]; --j; }
            el_s[j + 1] = key;
        }
    }
    __syncthreads();
    int mc = t & 127, hi = t >> 7;
    float acc[8];
    #pragma unroll
    for (int q = 0; q < 8; ++q) acc[q] = 0.f;
    for (int j = 0; j < k; ++j) {
        int e = (j < CAP) ? el_s[j] : elist[r0 + j];
        const float* Ae = A + (size_t)e * 512;
        const float* Ye = Y + e * 16 + hi * 8;
        float y[8];
        #pragma unroll
        for (int q = 0; q < 8; ++q) y[q] = Ye[q];
        if (hi == 0) {
            float a0 = Ae[mc], a1 = Ae[128 + mc], a2 = Ae[256 + mc];
            acc[0] += a0 * y[0];
            acc[1] += a1 * y[1]; acc[2] += a1 * y[2]; acc[3] += a1 * y[3];
            acc[4] += a2 * y[4]; acc[5] += a2 * y[5]; acc[6] += a2 * y[6]; acc[7] += a2 * y[7];
        } else {
            float a2 = Ae[256 + mc], a3 = Ae[384 + mc];
            acc[0] += a2 * y[0];
            #pragma unroll
            for (int q = 1; q < 8; ++q) acc[q] += a3 * y[q];
        }
    }
    #pragma unroll
    for (int q = 0; q < 8; ++q) msgs_s[mc * 17 + hi * 8 + q] = acc[q];
    __syncthreads();
    int z = 0;
    #pragma unroll
    for (int w = 1; w < 10; ++w)
        if (na[n * 10 + w] > 0.5f) z = w;
    float o[8];
    #pragma unroll
    for (int q = 0; q < 8; ++q) o[q] = 0.f;
    if (hi == 0) {
        const float* C0 = C + (0 * 10 + z) * 16384 + mc;
        const float* C1 = C + (1 * 10 + z) * 16384 + mc;
        const float* C2 = C + (2 * 10 + z) * 16384 + mc;
        #pragma unroll 4
        for (int u = 0; u < 128; ++u) {
            float c0 = C0[u * 128], c1 = C1[u * 128], c2 = C2[u * 128];
            const float* m = &msgs_s[u * 17];
            o[0] += m[0] * c0;
            o[1] += m[1] * c1; o[2] += m[2] * c1; o[3] += m[3] * c1;
            o[4] += m[4] * c2; o[5] += m[5] * c2; o[6] += m[6] * c2; o[7] += m[7] * c2;
        }
    } else {
        const float* C2 = C + (2 * 10 + z) * 16384 + mc;
        const float* C3 = C + (3 * 10 + z) * 16384 + mc;
        #pragma unroll 4
        for (int u = 0; u < 128; ++u) {
            float c2 = C2[u * 128], c3 = C3[u * 128];
            const float* m = &msgs_s[u * 17] + 8;
            o[0] += m[0] * c2;
            #pragma unroll
            for (int q = 1; q < 8; ++q) o[q] += m[q] * c3;
        }
    }
    #pragma unroll
    for (int q = 0; q < 8; ++q) out_s[mc * 17 + hi * 8 + q] = o[q];
    __syncthreads();
    int u_ = t >> 1;
    int dbase = (t & 1) * 8;
    const float* src = &out_s[u_ * 17 + dbase];
    float4 v0 = make_float4(src[0], src[1], src[2], src[3]);
    float4 v1 = make_float4(src[4], src[5], src[6], src[7]);
    float4* dst = (float4*)(out + (size_t)n * 2048 + t * 8);
    dst[0] = v0;
    dst[1] = v1;
}

extern "C" void kernel_launch(void* const* d_in, const int* in_sizes, int n_in,
                              void* d_out, int out_size, void* d_ws, size_t ws_size,
                              hipStream_t stream) {
    const float* na   = (const float*)d_in[0];
    const float* nf   = (const float*)d_in[1];
    const float* ea   = (const float*)d_in[2];
    const float* ef   = (const float*)d_in[3];
    const int*   eidx = (const int*)d_in[4];
    const float* Wup  = (const float*)d_in[5];
    const float* W1   = (const float*)d_in[6];
    const float* b1   = (const float*)d_in[7];
    const float* W2   = (const float*)d_in[8];
    const float* b2   = (const float*)d_in[9];
    const float* W3   = (const float*)d_in[10];
    const float* b3   = (const float*)d_in[11];
    const float* W4   = (const float*)d_in[12];
    const float* b4   = (const float*)d_in[13];
    const float* Wlin = (const float*)d_in[14];
    const float* Wskip= (const float*)d_in[15];
    float* out = (float*)d_out;

    char* ws = (char*)d_ws;
    float* A        = (float*)(ws + WS_A);
    float* x        = (float*)(ws + WS_X);
    float* C        = (float*)(ws + WS_C);
    int*   counts   = (int*)(ws + WS_COUNTS);
    int*   cursor   = (int*)(ws + WS_CURSOR);
    int*   rowstart = (int*)(ws + WS_ROWSTART);
    int*   elist    = (int*)(ws + WS_ELIST);

    hipMemsetAsync(counts, 0, NN * sizeof(int), stream);
    k_count<<<NE / 256, 256, 0, stream>>>(eidx, counts);
    k_scan<<<1, 1024, 0, stream>>>(counts, rowstart, cursor);
    k_scatter<<<NE / 256, 256, 0, stream>>>(eidx, cursor, elist);
    k_x<<<NN / 16, 256, 0, stream>>>(nf, Wup, x);
    k_C<<<320, 256, 0, stream>>>(Wlin, Wskip, C);
    k_edge<<<NE / 32, 256, 0, stream>>>(ef, eidx, W1, b1, W2, b2, W3, b3, W4, b4, x, A);
    k_gather<<<NN, 256, 0, stream>>>(A, ea, C, na, rowstart, elist, out);
}